// Round 6
// baseline (3296.626 us; speedup 1.0000x reference)
//
#include <hip/hip_runtime.h>
#include <hip/hip_bf16.h>

using bf16 = __hip_bfloat16;
typedef __attribute__((ext_vector_type(8))) short bf16x8;   // 8 bf16 (4 VGPRs)
typedef __attribute__((ext_vector_type(4))) float f32x4;

#define T_DIM 8192
#define DM    4096
#define DFF   14336

#define MFMA(va, vb, vc) __builtin_amdgcn_mfma_f32_16x16x32_bf16(va, vb, vc, 0, 0, 0)

// ---------------------------------------------------------------- helpers
__device__ __forceinline__ void gld_lds16(const bf16* gsrc, bf16* ldst) {
  auto* g = (const __attribute__((address_space(1))) unsigned int*)gsrc;
  auto* l = (__attribute__((address_space(3))) unsigned int*)ldst;
  __builtin_amdgcn_global_load_lds(g, l, 16, 0, 0);
}

// Stage one 8KB chunk (512 granules of 16B = 64 rows) of a [rows][64] bf16 tile.
// LDS dest linear (gld_lds requirement); GLOBAL source inverse-swizzled so
// reads apply  byte ^= ((row&7)<<4)  (T2, rule 21).
__device__ __forceinline__ void stage8k(const bf16* __restrict__ gbase, long lda,
                                        long grow0, long k0, bf16* lds_tile,
                                        int gran0, int tid) {
  const int g = gran0 + tid;            // granule index within tile
  const int row = g >> 3, c16 = g & 7;  // 8 granules (128B) per row
  const bf16* src = gbase + (grow0 + row) * lda + k0 + ((long)(c16 ^ (row & 7)) << 3);
  bf16* dst = lds_tile + ((size_t)(gran0 + (tid & ~63)) << 3);  // wave-uniform base
  gld_lds16(src, dst);
}

// Swizzled fragment read: 8 contiguous k (bf16) for MFMA A/B operand (16x16x32).
__device__ __forceinline__ bf16x8 ldsfrag(const bf16* tile, int row, int kk, int fg) {
  int addr = (row << 7) + (kk << 6) + (fg << 4);  // bytes; 128B per row
  addr ^= (row & 7) << 4;                          // T2 XOR swizzle
  return *reinterpret_cast<const bf16x8*>(reinterpret_cast<const char*>(tile) + addr);
}

#define PHASE_MFMA_BEGIN()                            \
  __builtin_amdgcn_s_barrier();                       \
  asm volatile("s_waitcnt lgkmcnt(0)" ::: "memory");  \
  __builtin_amdgcn_sched_barrier(0);                  \
  __builtin_amdgcn_s_setprio(1)

#define PHASE_MFMA_END()                              \
  __builtin_amdgcn_s_setprio(0);                      \
  __builtin_amdgcn_sched_barrier(0);                  \
  __builtin_amdgcn_s_barrier()

// ---------------------------------------------------------------- fp32 [T][DM] -> bf16 [T][xlda] (padded rows)
__global__ void cast_pad_kernel(const float* __restrict__ in,
                                bf16* __restrict__ out, long xlda, int n8) {
  int idx = blockIdx.x * blockDim.x + threadIdx.x;
  int stride = gridDim.x * blockDim.x;
  for (int i = idx; i < n8; i += stride) {
    const int row = i >> 9;              // DM/8 = 512 groups per row
    const int c8 = i & 511;
    const float4 v0 = reinterpret_cast<const float4*>(in)[(long)i * 2];
    const float4 v1 = reinterpret_cast<const float4*>(in)[(long)i * 2 + 1];
    bf16 t[8] = {__float2bfloat16(v0.x), __float2bfloat16(v0.y),
                 __float2bfloat16(v0.z), __float2bfloat16(v0.w),
                 __float2bfloat16(v1.x), __float2bfloat16(v1.y),
                 __float2bfloat16(v1.z), __float2bfloat16(v1.w)};
    *reinterpret_cast<bf16x8*>(&out[(long)row * xlda + (long)c8 * 8]) =
        *reinterpret_cast<bf16x8*>(t);
  }
}

// ---------------------------------------------------------------- fp32 [R][C] -> bf16 [C][out_lda] (transposed, padded rows)
__global__ void transpose_cast_kernel(const float* __restrict__ in,
                                      bf16* __restrict__ out, int R, int C,
                                      long out_lda) {
  __shared__ float tile[32][33];
  const int c0 = blockIdx.x * 32, r0 = blockIdx.y * 32;
  const int tx = threadIdx.x, ty = threadIdx.y;  // block (32,8)
#pragma unroll
  for (int j = 0; j < 4; ++j)
    tile[ty + j * 8][tx] = in[(long)(r0 + ty + j * 8) * C + (c0 + tx)];
  __syncthreads();
#pragma unroll
  for (int j = 0; j < 4; ++j)
    out[(long)(c0 + ty + j * 8) * out_lda + (r0 + tx)] =
        __float2bfloat16(tile[tx][ty + j * 8]);
}

// ---------------------------------------------------------------- GEMM1: gate+up fused (8-phase, m201 geometry)
// X:[T][ldx], Gt/Ut:[DFF][ldw] (W^T row-major, padded).
// Tile 256(M) x 256(N'): B rows 0-127 = Gt[fcol0..+128), 128-255 = Ut[fcol0..+128).
// XCD-partitioned: xcd owns 14 consecutive f-blocks; bm advances co-temporally.
// Staging (full-iteration prefetch): all 8 chunks of tile t+2 staged during
// step t, each strictly AFTER its region's last ds_read phase:
//   p2: A0 + B-gate (4)   [A0 read p1, Bg read p1]
//   p3: B-up (2)          [Bu read p2]
//   p4: A1 (2)            [A1 read p3]
// Single vmcnt(8) at p4 leaves exactly step-t's 8 issues outstanding ->
// tile t+1 (issued in step t-1, a full iteration earlier) is landed.
__global__ __launch_bounds__(512, 2) void gemm_gateup_kernel(
    const bf16* __restrict__ X, const bf16* __restrict__ Gt,
    const bf16* __restrict__ Ut, bf16* __restrict__ H,
    long ldx, long ldw, long ldh) {
  __shared__ __align__(16) bf16 sA[2][256 * 64];   // 64 KiB
  __shared__ __align__(16) bf16 sB[2][256 * 64];   // 64 KiB

  const int tid = threadIdx.x;
  const int lane = tid & 63, wid = tid >> 6;
  const int wm = wid >> 2, wn = wid & 3;
  const int fr = lane & 15, fg = lane >> 4;

  // XCD ownership: xcd = id&7 owns f-blocks [xcd*14, xcd*14+14); bm = j/14.
  const int id = blockIdx.x;
  const int xcd = id & 7, j = id >> 3;
  const int bm = j / 14, bnl = j % 14;
  const long row0 = (long)bm * 256;
  const long fcol0 = (long)(xcd * 14 + bnl) * 128;  // H col block == Gt/Ut row block
  const int NK = DM / 64;  // 64

  f32x4 acc[8][4];  // n=0,1: gate; n=2,3: up (same H cols)
  const f32x4 z = {0.f, 0.f, 0.f, 0.f};
#pragma unroll
  for (int m = 0; m < 8; ++m)
#pragma unroll
    for (int n = 0; n < 4; ++n) acc[m][n] = z;

  // prologue: tile0 full (8), tile1 full (8); drain tile0 (vmcnt(8)).
  stage8k(X, ldx, row0, 0, (bf16*)sA[0], 0, tid);
  stage8k(X, ldx, row0, 0, (bf16*)sA[0], 512, tid);
  stage8k(X, ldx, row0, 0, (bf16*)sA[0], 1024, tid);
  stage8k(X, ldx, row0, 0, (bf16*)sA[0], 1536, tid);
  stage8k(Gt, ldw, fcol0, 0, (bf16*)sB[0], 0, tid);
  stage8k(Gt, ldw, fcol0, 0, (bf16*)sB[0], 512, tid);
  stage8k(Ut, ldw, fcol0 - 128, 0, (bf16*)sB[0], 1024, tid);
  stage8k(Ut, ldw, fcol0 - 128, 0, (bf16*)sB[0], 1536, tid);
  stage8k(X, ldx, row0, 64, (bf16*)sA[1], 0, tid);
  stage8k(X, ldx, row0, 64, (bf16*)sA[1], 512, tid);
  stage8k(X, ldx, row0, 64, (bf16*)sA[1], 1024, tid);
  stage8k(X, ldx, row0, 64, (bf16*)sA[1], 1536, tid);
  stage8k(Gt, ldw, fcol0, 64, (bf16*)sB[1], 0, tid);
  stage8k(Gt, ldw, fcol0, 64, (bf16*)sB[1], 512, tid);
  stage8k(Ut, ldw, fcol0 - 128, 64, (bf16*)sB[1], 1024, tid);
  stage8k(Ut, ldw, fcol0 - 128, 64, (bf16*)sB[1], 1536, tid);
  asm volatile("s_waitcnt vmcnt(8)" ::: "memory");
  __builtin_amdgcn_s_barrier();

  bf16x8 a[4][2], b[4][2];

  for (int t = 0; t < NK; ++t) {
    bf16* aCur = (bf16*)sA[t & 1];
    bf16* bCur = (bf16*)sB[t & 1];
    const long k2 = (long)((t + 2) % NK) * 64;  // wrap: tail stages land harmlessly

    // ---- phase 1: read A-mh0 (8) + B-gate (4); MFMA Q(mh0, gate)
#pragma unroll
    for (int m = 0; m < 4; ++m)
#pragma unroll
      for (int kk = 0; kk < 2; ++kk)
        a[m][kk] = ldsfrag(aCur, m * 32 + wm * 16 + fr, kk, fg);
#pragma unroll
    for (int n = 0; n < 2; ++n)
#pragma unroll
      for (int kk = 0; kk < 2; ++kk)
        b[n][kk] = ldsfrag(bCur, n * 64 + wn * 16 + fr, kk, fg);
    PHASE_MFMA_BEGIN();
#pragma unroll
    for (int m = 0; m < 4; ++m)
#pragma unroll
      for (int n = 0; n < 2; ++n)
#pragma unroll
        for (int kk = 0; kk < 2; ++kk)
          acc[m][n] = MFMA(a[m][kk], b[n][kk], acc[m][n]);
    PHASE_MFMA_END();

    // ---- phase 2: read B-up (4); stage (t+2) A0 + B-gate; MFMA Q(mh0, up)
#pragma unroll
    for (int n = 2; n < 4; ++n)
#pragma unroll
      for (int kk = 0; kk < 2; ++kk)
        b[n][kk] = ldsfrag(bCur, n * 64 + wn * 16 + fr, kk, fg);
    stage8k(X, ldx, row0, k2, aCur, 0, tid);
    stage8k(X, ldx, row0, k2, aCur, 512, tid);
    stage8k(Gt, ldw, fcol0, k2, bCur, 0, tid);
    stage8k(Gt, ldw, fcol0, k2, bCur, 512, tid);
    PHASE_MFMA_BEGIN();
#pragma unroll
    for (int m = 0; m < 4; ++m)
#pragma unroll
      for (int n = 2; n < 4; ++n)
#pragma unroll
        for (int kk = 0; kk < 2; ++kk)
          acc[m][n] = MFMA(a[m][kk], b[n][kk], acc[m][n]);
    PHASE_MFMA_END();

    // ---- phase 3: read A-mh1 (8); stage (t+2) B-up; MFMA Q(mh1, up)
#pragma unroll
    for (int m = 0; m < 4; ++m)
#pragma unroll
      for (int kk = 0; kk < 2; ++kk)
        a[m][kk] = ldsfrag(aCur, 128 + m * 32 + wm * 16 + fr, kk, fg);
    stage8k(Ut, ldw, fcol0 - 128, k2, bCur, 1024, tid);
    stage8k(Ut, ldw, fcol0 - 128, k2, bCur, 1536, tid);
    PHASE_MFMA_BEGIN();
#pragma unroll
    for (int m = 0; m < 4; ++m)
#pragma unroll
      for (int n = 2; n < 4; ++n)
#pragma unroll
        for (int kk = 0; kk < 2; ++kk)
          acc[4 + m][n] = MFMA(a[m][kk], b[n][kk], acc[4 + m][n]);
    PHASE_MFMA_END();

    // ---- phase 4: stage (t+2) A1; vmcnt(8) -> tile t+1 landed; MFMA Q(mh1, gate)
    stage8k(X, ldx, row0, k2, aCur, 1024, tid);
    stage8k(X, ldx, row0, k2, aCur, 1536, tid);
    asm volatile("s_waitcnt vmcnt(8)" ::: "memory");
    PHASE_MFMA_BEGIN();
#pragma unroll
    for (int m = 0; m < 4; ++m)
#pragma unroll
      for (int n = 0; n < 2; ++n)
#pragma unroll
        for (int kk = 0; kk < 2; ++kk)
          acc[4 + m][n] = MFMA(a[m][kk], b[n][kk], acc[4 + m][n]);
    PHASE_MFMA_END();
  }

  // epilogue: H = bf16(silu(gate) * up) — register-only pairing.
  // Non-temporal stores: H is a pure stream; keep it out of L2/L3 so the
  // weight slices stay resident (fetch-pacing fix #2).
  unsigned short* Hu = reinterpret_cast<unsigned short*>(H);
#pragma unroll
  for (int m = 0; m < 8; ++m) {
    const long rbase = row0 + m * 32 + wm * 16 + fg * 4;
#pragma unroll
    for (int n = 0; n < 2; ++n) {
      const long c = fcol0 + n * 64 + wn * 16 + fr;
#pragma unroll
      for (int i = 0; i < 4; ++i) {
        float gv = acc[m][n][i];
        float uv = acc[m][n + 2][i];
        float hv = (gv / (1.0f + __expf(-gv))) * uv;
        union { bf16 b; unsigned short u; } cv;
        cv.b = __float2bfloat16(hv);
        __builtin_nontemporal_store(cv.u, Hu + (rbase + i) * ldh + c);
      }
    }
  }
}

// ---------------------------------------------------------------- GEMM2: out = routing*(H @ Wd)  (8-phase, m201 geometry)
// A:[T][ldh], Bt:[DM][lddt]. Tile 256x256, per-wave 128x64, acc[8][4].
// XCD-partitioned: xcd owns 2 col-blocks (512 cols); bm co-temporal.
// Staging: p2: A0+B0 (4), p3: B1 (2), p4: A1 (2); vmcnt(8) at p4.
__global__ __launch_bounds__(512, 2) void gemm_down_kernel(
    const bf16* __restrict__ A, const bf16* __restrict__ Bt,
    const float* __restrict__ routing, float* __restrict__ out,
    long ldh, long lddt) {
  __shared__ __align__(16) bf16 sA[2][256 * 64];   // 64 KiB
  __shared__ __align__(16) bf16 sB[2][256 * 64];   // 64 KiB

  const int tid = threadIdx.x;
  const int lane = tid & 63, wid = tid >> 6;
  const int wm = wid >> 2, wn = wid & 3;
  const int fr = lane & 15, fg = lane >> 4;

  const int id = blockIdx.x;
  const int xcd = id & 7, j = id >> 3;
  const int bm = j >> 1, bnl = j & 1;
  const long row0 = (long)bm * 256;
  const long col0 = (long)(xcd * 2 + bnl) * 256;
  const int NK = DFF / 64;  // 224

  f32x4 acc[8][4];
  const f32x4 z = {0.f, 0.f, 0.f, 0.f};
#pragma unroll
  for (int m = 0; m < 8; ++m)
#pragma unroll
    for (int n = 0; n < 4; ++n) acc[m][n] = z;

  // prologue: tile0 full (8), tile1 full (8); drain tile0.
  stage8k(A, ldh, row0, 0, (bf16*)sA[0], 0, tid);
  stage8k(A, ldh, row0, 0, (bf16*)sA[0], 512, tid);
  stage8k(A, ldh, row0, 0, (bf16*)sA[0], 1024, tid);
  stage8k(A, ldh, row0, 0, (bf16*)sA[0], 1536, tid);
  stage8k(Bt, lddt, col0, 0, (bf16*)sB[0], 0, tid);
  stage8k(Bt, lddt, col0, 0, (bf16*)sB[0], 512, tid);
  stage8k(Bt, lddt, col0, 0, (bf16*)sB[0], 1024, tid);
  stage8k(Bt, lddt, col0, 0, (bf16*)sB[0], 1536, tid);
  stage8k(A, ldh, row0, 64, (bf16*)sA[1], 0, tid);
  stage8k(A, ldh, row0, 64, (bf16*)sA[1], 512, tid);
  stage8k(A, ldh, row0, 64, (bf16*)sA[1], 1024, tid);
  stage8k(A, ldh, row0, 64, (bf16*)sA[1], 1536, tid);
  stage8k(Bt, lddt, col0, 64, (bf16*)sB[1], 0, tid);
  stage8k(Bt, lddt, col0, 64, (bf16*)sB[1], 512, tid);
  stage8k(Bt, lddt, col0, 64, (bf16*)sB[1], 1024, tid);
  stage8k(Bt, lddt, col0, 64, (bf16*)sB[1], 1536, tid);
  asm volatile("s_waitcnt vmcnt(8)" ::: "memory");
  __builtin_amdgcn_s_barrier();

  bf16x8 a[4][2], b[4][2];

  for (int t = 0; t < NK; ++t) {
    bf16* aCur = (bf16*)sA[t & 1];
    bf16* bCur = (bf16*)sB[t & 1];
    const long k2 = (long)((t + 2) % NK) * 64;

    // ---- phase 1: read A-mh0 (8) + B-nh0 (4); MFMA Q(mh0,nh0)
#pragma unroll
    for (int m = 0; m < 4; ++m)
#pragma unroll
      for (int kk = 0; kk < 2; ++kk)
        a[m][kk] = ldsfrag(aCur, m * 32 + wm * 16 + fr, kk, fg);
#pragma unroll
    for (int n = 0; n < 2; ++n)
#pragma unroll
      for (int kk = 0; kk < 2; ++kk)
        b[n][kk] = ldsfrag(bCur, n * 64 + wn * 16 + fr, kk, fg);
    PHASE_MFMA_BEGIN();
#pragma unroll
    for (int m = 0; m < 4; ++m)
#pragma unroll
      for (int n = 0; n < 2; ++n)
#pragma unroll
        for (int kk = 0; kk < 2; ++kk)
          acc[m][n] = MFMA(a[m][kk], b[n][kk], acc[m][n]);
    PHASE_MFMA_END();

    // ---- phase 2: read B-nh1 (4); stage (t+2) A0+B0; MFMA Q(mh0,nh1)
#pragma unroll
    for (int n = 2; n < 4; ++n)
#pragma unroll
      for (int kk = 0; kk < 2; ++kk)
        b[n][kk] = ldsfrag(bCur, n * 64 + wn * 16 + fr, kk, fg);
    stage8k(A, ldh, row0, k2, aCur, 0, tid);
    stage8k(A, ldh, row0, k2, aCur, 512, tid);
    stage8k(Bt, lddt, col0, k2, bCur, 0, tid);
    stage8k(Bt, lddt, col0, k2, bCur, 512, tid);
    PHASE_MFMA_BEGIN();
#pragma unroll
    for (int m = 0; m < 4; ++m)
#pragma unroll
      for (int n = 2; n < 4; ++n)
#pragma unroll
        for (int kk = 0; kk < 2; ++kk)
          acc[m][n] = MFMA(a[m][kk], b[n][kk], acc[m][n]);
    PHASE_MFMA_END();

    // ---- phase 3: read A-mh1 (8); stage (t+2) B1; MFMA Q(mh1,nh1)
#pragma unroll
    for (int m = 0; m < 4; ++m)
#pragma unroll
      for (int kk = 0; kk < 2; ++kk)
        a[m][kk] = ldsfrag(aCur, 128 + m * 32 + wm * 16 + fr, kk, fg);
    stage8k(Bt, lddt, col0, k2, bCur, 1024, tid);
    stage8k(Bt, lddt, col0, k2, bCur, 1536, tid);
    PHASE_MFMA_BEGIN();
#pragma unroll
    for (int m = 0; m < 4; ++m)
#pragma unroll
      for (int n = 2; n < 4; ++n)
#pragma unroll
        for (int kk = 0; kk < 2; ++kk)
          acc[4 + m][n] = MFMA(a[m][kk], b[n][kk], acc[4 + m][n]);
    PHASE_MFMA_END();

    // ---- phase 4: stage (t+2) A1; vmcnt(8); MFMA Q(mh1,nh0)
    stage8k(A, ldh, row0, k2, aCur, 1024, tid);
    stage8k(A, ldh, row0, k2, aCur, 1536, tid);
    asm volatile("s_waitcnt vmcnt(8)" ::: "memory");
    PHASE_MFMA_BEGIN();
#pragma unroll
    for (int m = 0; m < 4; ++m)
#pragma unroll
      for (int n = 0; n < 2; ++n)
#pragma unroll
        for (int kk = 0; kk < 2; ++kk)
          acc[4 + m][n] = MFMA(a[m][kk], b[n][kk], acc[4 + m][n]);
    PHASE_MFMA_END();
  }

  // epilogue: out = routing[r] * acc  (non-temporal: out is never re-read)
#pragma unroll
  for (int m = 0; m < 8; ++m) {
    const long r0w = row0 + m * 32 + wm * 16 + fg * 4;
#pragma unroll
    for (int i = 0; i < 4; ++i) {
      const long r = r0w + i;
      const float rv = routing[r];
#pragma unroll
      for (int n = 0; n < 4; ++n)
        __builtin_nontemporal_store(rv * acc[m][n][i],
                                    &out[r * DM + (col0 + n * 64 + wn * 16 + fr)]);
    }
  }
}

// ---------------------------------------------------------------- launch
extern "C" void kernel_launch(void* const* d_in, const int* in_sizes, int n_in,
                              void* d_out, int out_size, void* d_ws, size_t ws_size,
                              hipStream_t stream) {
  const float* X  = (const float*)d_in[0];
  const float* rw = (const float*)d_in[1];
  const float* Wg = (const float*)d_in[2];
  const float* Wu = (const float*)d_in[3];
  const float* Wd = (const float*)d_in[4];
  float* out = (float*)d_out;

  // Padded leading dims (break power-of-2 row strides: 4160*2=65*128B,
  // 14400*2=225*128B). Fall back to unpadded if workspace is tight.
  long XL = DM + 64, WL = DM + 64, DL = DFF + 64, HL = DFF + 64;
  {
    size_t need = 2ull * ((size_t)T_DIM * XL + 2ull * (size_t)DFF * WL +
                          (size_t)DM * DL + (size_t)T_DIM * HL);
    if (ws_size < need) { XL = DM; WL = DM; DL = DFF; HL = DFF; }
  }

  char* ws = (char*)d_ws;
  size_t off = 0;
  bf16* Xb = (bf16*)(ws + off); off += (size_t)T_DIM * XL * 2;
  bf16* GT = (bf16*)(ws + off); off += (size_t)DFF * WL * 2;
  bf16* UT = (bf16*)(ws + off); off += (size_t)DFF * WL * 2;
  bf16* DT = (bf16*)(ws + off); off += (size_t)DM * DL * 2;
  bf16* Hb = (bf16*)(ws + off); off += (size_t)T_DIM * HL * 2;

  cast_pad_kernel<<<2048, 256, 0, stream>>>(X, Xb, XL, T_DIM * DM / 8);
  dim3 tpb(32, 8);
  transpose_cast_kernel<<<dim3(DFF / 32, DM / 32), tpb, 0, stream>>>(Wg, GT, DM, DFF, WL);
  transpose_cast_kernel<<<dim3(DFF / 32, DM / 32), tpb, 0, stream>>>(Wu, UT, DM, DFF, WL);
  transpose_cast_kernel<<<dim3(DM / 32, DFF / 32), tpb, 0, stream>>>(Wd, DT, DFF, DM, DL);

  gemm_gateup_kernel<<<(T_DIM / 256) * (DFF / 128), 512, 0, stream>>>(
      Xb, GT, UT, Hb, XL, WL, HL);
  gemm_down_kernel<<<(T_DIM / 256) * (DM / 256), 512, 0, stream>>>(
      Hb, DT, rw, out, HL, DL);
}